// Round 4
// baseline (279.746 us; speedup 1.0000x reference)
//
#include <hip/hip_runtime.h>

// Volume-rendering composite: B=65536 rays, N=128 samples/ray.
// R3 (resubmit after broker timeout): ALL global loads unit-stride. Colors
// loaded as wave-contiguous float4 blocks; weights (256 floats/wave)
// redistributed via LDS; channel attribution is a static rotation by f%3.

constexpr int RAYS = 65536;
constexpr int NS   = 128;
constexpr int WPB  = 4;          // waves per block (256 threads), 2 rays/wave

// x += dpp_shifted(x); invalid source lanes contribute 0 (bound_ctrl).
#define DPP_ADD(x, ctrl, rm)                                                   \
    x += __int_as_float(__builtin_amdgcn_update_dpp(                           \
        0, __float_as_int(x), ctrl, rm, 0xf, true))

// Inclusive prefix sum over each 32-lane half.
__device__ __forceinline__ float scan32(float x) {
    DPP_ADD(x, 0x111, 0xf);   // row_shr:1
    DPP_ADD(x, 0x112, 0xf);   // row_shr:2
    DPP_ADD(x, 0x114, 0xf);   // row_shr:4
    DPP_ADD(x, 0x118, 0xf);   // row_shr:8
    DPP_ADD(x, 0x142, 0xa);   // row_bcast:15 into rows 1,3
    return x;
}

__global__ __launch_bounds__(256) void render_composite_kernel(
    const float* __restrict__ density,   // [B, N]
    const float* __restrict__ deltas,    // [B, N]
    const float* __restrict__ zs,        // [B, N]
    const float* __restrict__ rgbs,      // [B, N, 3]
    const float* __restrict__ normals,   // [B, N, 3]
    float* __restrict__ out)             // [B, 8]
{
    __shared__ __align__(16) float wlds[WPB][256];   // per-wave weight table

    const int tid  = threadIdx.x;
    const int wv   = tid >> 6;
    const int l    = tid & 63;
    const int k    = l & 31;            // lane within ray (scalar part)
    const int half = l >> 5;

    const int ray0 = (blockIdx.x * WPB + wv) * 2;    // wave owns rays ray0, ray0+1
    const int ray  = ray0 + half;

    // ---- scalar loads: wave covers both rays' rows contiguously (1KB) ----
    const size_t row = (size_t)ray * NS;
    const float4 d  = reinterpret_cast<const float4*>(density + row)[k];
    const float4 dl = reinterpret_cast<const float4*>(deltas  + row)[k];
    const float4 z  = reinterpret_cast<const float4*>(zs      + row)[k];

    // ---- color loads: 3 wave-contiguous float4 instrs per array (3KB) ----
    const float4* cr = reinterpret_cast<const float4*>(rgbs)    + (size_t)ray0 * 96;
    const float4* cn = reinterpret_cast<const float4*>(normals) + (size_t)ray0 * 96;
    const float4 vr0 = cr[0 * 64 + l];
    const float4 vr1 = cr[1 * 64 + l];
    const float4 vr2 = cr[2 * 64 + l];
    const float4 vn0 = cn[0 * 64 + l];
    const float4 vn1 = cn[1 * 64 + l];
    const float4 vn2 = cn[2 * 64 + l];

    // ---- weights: sigma*delta scan (per 32-lane half) ----
    const float s0 = d.x * dl.x;
    const float s1 = d.y * dl.y;
    const float s2 = d.z * dl.z;
    const float s3 = d.w * dl.w;
    const float slocal = (s0 + s1) + (s2 + s3);
    const float prefix = scan32(slocal);
    const float S0 = prefix - slocal;

    const float e0 = __expf(-S0);
    const float e1 = __expf(-(S0 + s0));
    const float e2 = __expf(-(S0 + s0 + s1));
    const float e3 = __expf(-(S0 + s0 + s1 + s2));
    const float e4 = __expf(-(S0 + slocal));
    const float w0 = e0 - e1, w1 = e1 - e2, w2 = e2 - e3, w3 = e3 - e4;

    float acc_w  = (w0 + w1) + (w2 + w3);
    float acc_wz = w0 * z.x + w1 * z.y + w2 * z.z + w3 * z.w;

    // ---- publish weights: float idx 4*l == half*128 + 4k (wave-sample order) ----
    reinterpret_cast<float4*>(&wlds[wv][0])[l] = make_float4(w0, w1, w2, w3);
    const float* wbase = &wlds[wv][0];

    // ---- per-lane channel partials (ray0 / ray1, rgb / normal) ----
    float r0c0 = 0.f, r0c1 = 0.f, r0c2 = 0.f;
    float r1c0 = 0.f, r1c1 = 0.f, r1c2 = 0.f;
    float m0c0 = 0.f, m0c1 = 0.f, m0c2 = 0.f;
    float m1c0 = 0.f, m1c1 = 0.f, m1c2 = 0.f;

    // lane's float4 at wave-local float idx f covers floats f..f+3:
    //   x: sample q,   channel rt
    //   y: sample q+(rt==2), channel (rt+1)%3
    //   z: sample q+(rt>=1), channel (rt+2)%3
    //   w: sample q+1, channel rt
    // rotate (q0,q1,q2) [channels rt, rt+1, rt+2] into absolute channels.
    auto proc = [](const float4 v, float wA, float wB, int rt,
                   float& c0, float& c1, float& c2) {
        const float q0 = wA * v.x + wB * v.w;
        const float q1 = ((rt == 2) ? wB : wA) * v.y;
        const float q2 = ((rt >= 1) ? wB : wA) * v.z;
        const float a0 = (rt == 0) ? q0 : (rt == 1) ? q2 : q1;
        const float a1 = (rt == 0) ? q1 : (rt == 1) ? q0 : q2;
        const float a2 = (rt == 0) ? q2 : (rt == 1) ? q1 : q0;
        c0 += a0; c1 += a1; c2 += a2;
    };

    #pragma unroll
    for (int t = 0; t < 3; ++t) {
        const int f  = 256 * t + 4 * l;       // wave-local float index
        const int q  = f / 3;                 // wave-local sample (magic mul)
        const int rt = f - 3 * q;             // f % 3
        const float wA = wbase[q];
        const float wB = wbase[q + 1];
        const float4 vr = (t == 0) ? vr0 : (t == 1) ? vr1 : vr2;
        const float4 vn = (t == 0) ? vn0 : (t == 1) ? vn1 : vn2;

        if (t == 0) {                          // all ray0
            proc(vr, wA, wB, rt, r0c0, r0c1, r0c2);
            proc(vn, wA, wB, rt, m0c0, m0c1, m0c2);
        } else if (t == 2) {                   // all ray1
            proc(vr, wA, wB, rt, r1c0, r1c1, r1c2);
            proc(vn, wA, wB, rt, m1c0, m1c1, m1c2);
        } else {                               // split at lane 32 (f==384)
            float t0 = 0.f, t1c = 0.f, t2c = 0.f, u0 = 0.f, u1 = 0.f, u2 = 0.f;
            proc(vr, wA, wB, rt, t0, t1c, t2c);
            proc(vn, wA, wB, rt, u0, u1, u2);
            const bool isr0 = (l < 32);
            r0c0 += isr0 ? t0 : 0.f;  r1c0 += isr0 ? 0.f : t0;
            r0c1 += isr0 ? t1c : 0.f; r1c1 += isr0 ? 0.f : t1c;
            r0c2 += isr0 ? t2c : 0.f; r1c2 += isr0 ? 0.f : t2c;
            m0c0 += isr0 ? u0 : 0.f;  m1c0 += isr0 ? 0.f : u0;
            m0c1 += isr0 ? u1 : 0.f;  m1c1 += isr0 ? 0.f : u1;
            m0c2 += isr0 ? u2 : 0.f;  m1c2 += isr0 ? 0.f : u2;
        }
    }

    // ---- merge halves + per-half scan: lane31 -> ray0 total, lane63 -> ray1 ----
    auto reduce2 = [&](float cR0, float cR1) -> float {
        const float sel = half ? cR1 : cR0;   // partial for own half's ray
        const float oth = half ? cR0 : cR1;   // partial belonging to other ray
        const float m = sel + __shfl_xor(oth, 32, 64);
        return scan32(m);
    };
    const float R  = reduce2(r0c0, r1c0);
    const float G  = reduce2(r0c1, r1c1);
    const float Bc = reduce2(r0c2, r1c2);
    const float NR = reduce2(m0c0, m1c0);
    const float NG = reduce2(m0c1, m1c1);
    const float NB = reduce2(m0c2, m1c2);
    acc_w  = scan32(acc_w);
    acc_wz = scan32(acc_wz);

    if (k == 31) {
        const float depth = acc_wz / (acc_w + 1e-8f);
        float4* o = reinterpret_cast<float4*>(out + (size_t)ray * 8);
        o[0] = make_float4(R, G, Bc, depth);
        o[1] = make_float4(NR, NG, NB, acc_w);
    }
}

extern "C" void kernel_launch(void* const* d_in, const int* in_sizes, int n_in,
                              void* d_out, int out_size, void* d_ws, size_t ws_size,
                              hipStream_t stream) {
    const float* density = (const float*)d_in[0];
    const float* deltas  = (const float*)d_in[1];
    const float* zs      = (const float*)d_in[2];
    const float* rgbs    = (const float*)d_in[3];
    const float* normals = (const float*)d_in[4];
    float* out = (float*)d_out;

    const int grid = RAYS / (WPB * 2);              // 8192 blocks
    render_composite_kernel<<<grid, 256, 0, stream>>>(
        density, deltas, zs, rgbs, normals, out);
}